// Round 5
// baseline (702.421 us; speedup 1.0000x reference)
//
#include <hip/hip_runtime.h>
#include <hip/hip_bf16.h>

typedef float f32x4 __attribute__((ext_vector_type(4)));
typedef __bf16 bf16x8 __attribute__((ext_vector_type(8)));

static __device__ __forceinline__ unsigned short f2bf(float f) {
    unsigned int u = __float_as_uint(f);
    unsigned int r = (u + 0x7fffu + ((u >> 16) & 1u)) >> 16;   // RNE
    return (unsigned short)r;
}

// async global->LDS, 16B per lane; LDS dest = wave-uniform base + lane*16
static __device__ __forceinline__ void gll16(const void* g, void* l) {
    __builtin_amdgcn_global_load_lds(
        (const __attribute__((address_space(1))) unsigned int*)g,
        (__attribute__((address_space(3))) unsigned int*)l, 16, 0, 0);
}

// ---------------------------------------------------------------------------
// prep: pack both conv weights into tile-major MFMA-ready layout + cumsum.
// ---------------------------------------------------------------------------
template<int REP>
__global__ __launch_bounds__(512) void prep(
    const float* __restrict__ w1, const float* __restrict__ w2,
    unsigned short* __restrict__ w1p, unsigned short* __restrict__ w2p,
    const int* __restrict__ tgt, int* __restrict__ cum)
{
    int blk = blockIdx.x;
    if (blk < 768) {
        for (int rep = 0; rep < REP; ++rep) {
            int gi = blk * 512 + threadIdx.x;            // 0..393215
            const float* w = (gi < 196608) ? w1 : w2;
            unsigned short* wp = (gi < 196608) ? w1p : w2p;
            int j = (gi < 196608) ? gi : gi - 196608;    // 0..196607
            int e = j & 7;
            int ch = j >> 3;                             // 0..24575
            int kt = ch >> 10;                           // 0..23
            int rem = ch & 1023;
            int nb = rem >> 6, l = rem & 63;
            int n = nb * 16 + (l & 15);
            int cin = (kt & 7) * 32 + (l >> 4) * 8 + e;
            int kk = kt >> 3;
            wp[j] = f2bf(w[n * 768 + cin * 3 + kk]);
            asm volatile("" ::: "memory");
        }
    } else {
        __shared__ int s[512];
        for (int rep = 0; rep < REP; ++rep) {
            __syncthreads();
            int b = blk - 768, tid = threadIdx.x;
            s[tid] = tgt[b * 512 + tid];
            __syncthreads();
            for (int off = 1; off < 512; off <<= 1) {
                int v = (tid >= off) ? s[tid - off] : 0;
                __syncthreads();
                s[tid] += v;
                __syncthreads();
            }
            cum[b * 512 + tid] = s[tid];
            asm volatile("" ::: "memory");
        }
    }
}

// ---------------------------------------------------------------------------
// gather part (shared by both hetero kernels): 32 mel rows / block, 8 waves
// ---------------------------------------------------------------------------
static __device__ __forceinline__ void gather_part(
    int gblk, int phase, const float* __restrict__ x, const int* __restrict__ cum,
    float* __restrict__ out, int M, int wv, int lane)
{
    int b = gblk / 56;
    int r0 = (gblk % 56) * 32 + phase;
    const int* c = cum + b * 512;
    int total = c[511];
    #pragma unroll
    for (int i = 0; i < 4; ++i) {
        int m = r0 + i * 8 + wv;
        float4 v = make_float4(0.f, 0.f, 0.f, 0.f);
        if (m < total) {
            int lo = 0, hi = 512;
            while (lo < hi) { int mid = (lo + hi) >> 1; if (c[mid] <= m) lo = mid + 1; else hi = mid; }
            int idx = lo < 512 ? lo : 511;
            v = *reinterpret_cast<const float4*>(x + ((size_t)(b * 512 + idx)) * 256 + lane * 4);
        }
        *reinterpret_cast<float4*>(out + ((size_t)b * M + m) * 256 + lane * 4) = v;
    }
}

// ---------------------------------------------------------------------------
// conv1 + gather(first half). BM=64, BN=256, BK=32 (24 tiles), 8 waves 2Mx4N.
// ---------------------------------------------------------------------------
template<int REP>
__global__ __launch_bounds__(512, 4) void conv1_hetero(
    const float* __restrict__ x, const unsigned short* __restrict__ Wp,
    const float* __restrict__ bias, const float* __restrict__ g,
    const float* __restrict__ be, unsigned short* __restrict__ h1b,
    const int* __restrict__ cum, float* __restrict__ out, int M)
{
    __shared__ __align__(16) unsigned short As[66 * 256];
    __shared__ __align__(16) unsigned short Bsm[2][8192];
    __shared__ float lnS[4][64], lnQ[4][64];

    const int tid = threadIdx.x;
    const int lane = tid & 63;
    const int wv = tid >> 6;

    if (blockIdx.x >= 256) {
        for (int rep = 0; rep < REP; ++rep) {
            gather_part(blockIdx.x - 256, 0, x, cum, out, M, wv, lane);
            asm volatile("" ::: "memory");
        }
        return;
    }

    const int wmi = wv >> 2, wni = wv & 3;
    const int grp = lane >> 4, lr = lane & 15;
    const int b = blockIdx.x >> 3;
    const int t_base = (blockIdx.x & 7) * 64;

    const char* wpB = (const char*)Wp;
    char* bs0 = (char*)&Bsm[0][0];
    #define STAGE_B(kt, buf) do {                                              \
        const char* _s = wpB + (kt) * 16384 + wv * 2048 + lane * 16;           \
        char* _d = bs0 + (buf) * 16384 + wv * 2048;                            \
        gll16(_s, _d); gll16(_s + 1024, _d + 1024);                            \
    } while (0)

    for (int rep = 0; rep < REP; ++rep) {
        __syncthreads();   // protect As/Bsm reuse across reps (no-op cost at REP=1)

        // ---- A stage: x rows t_base-1 .. t_base+64 -> bf16, XOR-swizzled (row&7)<<3
        #pragma unroll
        for (int i = 0; i < 9; ++i) {
            int cc = i * 512 + tid;
            if (cc < 66 * 64) {
                int row = cc >> 6, q = cc & 63;
                int tt = t_base - 1 + row;
                ushort4 o = make_ushort4(0, 0, 0, 0);
                if ((unsigned)tt < 512u) {
                    float4 v = *reinterpret_cast<const float4*>(x + ((size_t)(b * 512 + tt)) * 256 + q * 4);
                    o.x = f2bf(v.x); o.y = f2bf(v.y); o.z = f2bf(v.z); o.w = f2bf(v.w);
                }
                *reinterpret_cast<ushort4*>(&As[row * 256 + ((q * 4) ^ ((row & 7) << 3))]) = o;
            }
        }

        STAGE_B(0, 0);
        __syncthreads();

        f32x4 acc[2][4] = {};
        int cur = 0;
        for (int kt = 0; kt < 24; ++kt) {
            if (kt < 23) STAGE_B(kt + 1, cur ^ 1);
            const int kk = kt >> 3, cin0 = (kt & 7) * 32;
            bf16x8 af[2], bfr[4];
            #pragma unroll
            for (int mi = 0; mi < 2; ++mi) {
                int tr = wmi * 32 + mi * 16 + lr + kk;
                af[mi] = *reinterpret_cast<const bf16x8*>(&As[tr * 256 + ((cin0 + grp * 8) ^ ((tr & 7) << 3))]);
            }
            #pragma unroll
            for (int ni = 0; ni < 4; ++ni)
                bfr[ni] = *reinterpret_cast<const bf16x8*>(&Bsm[cur][(wni * 4 + ni) * 512 + lane * 8]);
            __builtin_amdgcn_s_setprio(1);
            #pragma unroll
            for (int mi = 0; mi < 2; ++mi)
                #pragma unroll
                for (int ni = 0; ni < 4; ++ni)
                    acc[mi][ni] = __builtin_amdgcn_mfma_f32_16x16x32_bf16(af[mi], bfr[ni], acc[mi][ni], 0, 0, 0);
            __builtin_amdgcn_s_setprio(0);
            __syncthreads();
            cur ^= 1;
        }

        // ---- epilogue: bias+relu, LN, LDS-staged vectorized bf16 store
        float bcol[4], gcol[4], becol[4];
        #pragma unroll
        for (int ni = 0; ni < 4; ++ni) {
            int col = wni * 64 + ni * 16 + lr;
            bcol[ni] = bias[col]; gcol[ni] = g[col]; becol[ni] = be[col];
        }
        #pragma unroll
        for (int mi = 0; mi < 2; ++mi)
            #pragma unroll
            for (int ni = 0; ni < 4; ++ni)
                #pragma unroll
                for (int r = 0; r < 4; ++r)
                    acc[mi][ni][r] = fmaxf(acc[mi][ni][r] + bcol[ni], 0.f);

        #pragma unroll
        for (int mi = 0; mi < 2; ++mi)
            #pragma unroll
            for (int r = 0; r < 4; ++r) {
                float s = acc[mi][0][r] + acc[mi][1][r] + acc[mi][2][r] + acc[mi][3][r];
                float q = acc[mi][0][r] * acc[mi][0][r] + acc[mi][1][r] * acc[mi][1][r]
                        + acc[mi][2][r] * acc[mi][2][r] + acc[mi][3][r] * acc[mi][3][r];
                #pragma unroll
                for (int off = 1; off < 16; off <<= 1) {
                    s += __shfl_xor(s, off);
                    q += __shfl_xor(q, off);
                }
                if (lr == 0) {
                    int R = wmi * 32 + mi * 16 + grp * 4 + r;
                    lnS[wni][R] = s; lnQ[wni][R] = q;
                }
            }
        __syncthreads();

        unsigned short* Hs = &Bsm[0][0];   // 32 KB, dead after K-loop
        #pragma unroll
        for (int mi = 0; mi < 2; ++mi)
            #pragma unroll
            for (int r = 0; r < 4; ++r) {
                int R = wmi * 32 + mi * 16 + grp * 4 + r;
                float mu = (lnS[0][R] + lnS[1][R] + lnS[2][R] + lnS[3][R]) * (1.f / 256.f);
                float var = (lnQ[0][R] + lnQ[1][R] + lnQ[2][R] + lnQ[3][R]) * (1.f / 256.f) - mu * mu;
                float rs = rsqrtf(var + 1e-5f);
                #pragma unroll
                for (int ni = 0; ni < 4; ++ni) {
                    int col = wni * 64 + ni * 16 + lr;
                    float h = (acc[mi][ni][r] - mu) * rs * gcol[ni] + becol[ni];
                    Hs[R * 256 + (col ^ ((R & 7) << 3))] = f2bf(h);   // keep conv2's swizzle
                }
            }
        __syncthreads();
        // linear copy preserves the baked-in swizzle; fully coalesced 16B stores
        #pragma unroll
        for (int i = 0; i < 4; ++i) {
            int c = i * 512 + tid;          // 2048 chunks of 16B
            int row = c >> 5, seg = c & 31;
            uint4 v = *reinterpret_cast<const uint4*>(&Hs[row * 256 + seg * 8]);
            *reinterpret_cast<uint4*>(h1b + ((size_t)(b * 512 + t_base + row)) * 256 + seg * 8) = v;
        }
        asm volatile("" ::: "memory");
    }
    #undef STAGE_B
}

// ---------------------------------------------------------------------------
// conv2 + LN + linear + relu -> dur, + gather(second half)
// ---------------------------------------------------------------------------
template<int REP>
__global__ __launch_bounds__(512, 4) void conv2_hetero(
    const unsigned short* __restrict__ h1b, const unsigned short* __restrict__ Wp,
    const float* __restrict__ bias, const float* __restrict__ g,
    const float* __restrict__ be, const float* __restrict__ lw,
    const float* __restrict__ lb, float* __restrict__ dur,
    const int* __restrict__ cum, const float* __restrict__ x,
    float* __restrict__ out, int M)
{
    __shared__ __align__(16) unsigned short As[66 * 256];
    __shared__ __align__(16) unsigned short Bsm[2][8192];
    __shared__ float lnS[4][64], lnQ[4][64], lnD[4][64];

    const int tid = threadIdx.x;
    const int lane = tid & 63;
    const int wv = tid >> 6;

    if (blockIdx.x >= 256) {
        for (int rep = 0; rep < REP; ++rep) {
            gather_part(blockIdx.x - 256, 1792, x, cum, out, M, wv, lane);
            asm volatile("" ::: "memory");
        }
        return;
    }

    const int wmi = wv >> 2, wni = wv & 3;
    const int grp = lane >> 4, lr = lane & 15;
    const int b = blockIdx.x >> 3;
    const int t_base = (blockIdx.x & 7) * 64;

    const char* wpB = (const char*)Wp;
    char* bs0 = (char*)&Bsm[0][0];
    #define STAGE_B(kt, buf) do {                                              \
        const char* _s = wpB + (kt) * 16384 + wv * 2048 + lane * 16;           \
        char* _d = bs0 + (buf) * 16384 + wv * 2048;                            \
        gll16(_s, _d); gll16(_s + 1024, _d + 1024);                            \
    } while (0)

    for (int rep = 0; rep < REP; ++rep) {
        __syncthreads();

        // ---- A stage: interior rows 1..64 via global_load_lds (h1b is pre-swizzled)
        {
            const char* src = (const char*)h1b + ((size_t)(b * 512 + t_base)) * 512 + wv * 4096 + lane * 16;
            char* dst = (char*)&As[256] + wv * 4096;
            #pragma unroll
            for (int i = 0; i < 4; ++i) gll16(src + i * 1024, dst + i * 1024);
        }
        // halo rows 0 (t_base-1) and 65 (t_base+64), zero-padded
        if (tid < 32) {
            int tt = t_base - 1;
            uint4 v = make_uint4(0u, 0u, 0u, 0u);
            if (tt >= 0)
                v = *reinterpret_cast<const uint4*>((const char*)h1b + ((size_t)(b * 512 + tt)) * 512 + tid * 16);
            *reinterpret_cast<uint4*>((char*)As + tid * 16) = v;
        } else if (tid < 64) {
            int t2 = tid - 32, tt = t_base + 64;
            uint4 v = make_uint4(0u, 0u, 0u, 0u);
            if (tt < 512)
                v = *reinterpret_cast<const uint4*>((const char*)h1b + ((size_t)(b * 512 + tt)) * 512 + t2 * 16);
            *reinterpret_cast<uint4*>((char*)&As[65 * 256] + t2 * 16) = v;
        }

        STAGE_B(0, 0);
        __syncthreads();

        f32x4 acc[2][4] = {};
        int cur = 0;
        for (int kt = 0; kt < 24; ++kt) {
            if (kt < 23) STAGE_B(kt + 1, cur ^ 1);
            const int kk = kt >> 3, cin0 = (kt & 7) * 32;
            bf16x8 af[2], bfr[4];
            #pragma unroll
            for (int mi = 0; mi < 2; ++mi) {
                int tr = wmi * 32 + mi * 16 + lr + kk;
                af[mi] = *reinterpret_cast<const bf16x8*>(&As[tr * 256 + ((cin0 + grp * 8) ^ (((tr + 7) & 7) << 3))]);
            }
            #pragma unroll
            for (int ni = 0; ni < 4; ++ni)
                bfr[ni] = *reinterpret_cast<const bf16x8*>(&Bsm[cur][(wni * 4 + ni) * 512 + lane * 8]);
            __builtin_amdgcn_s_setprio(1);
            #pragma unroll
            for (int mi = 0; mi < 2; ++mi)
                #pragma unroll
                for (int ni = 0; ni < 4; ++ni)
                    acc[mi][ni] = __builtin_amdgcn_mfma_f32_16x16x32_bf16(af[mi], bfr[ni], acc[mi][ni], 0, 0, 0);
            __builtin_amdgcn_s_setprio(0);
            __syncthreads();
            cur ^= 1;
        }

        // ---- epilogue: bias+relu, LN, dot lin_w, relu -> dur[64]
        float bcol[4], gcol[4], becol[4], wcol[4];
        #pragma unroll
        for (int ni = 0; ni < 4; ++ni) {
            int col = wni * 64 + ni * 16 + lr;
            bcol[ni] = bias[col]; gcol[ni] = g[col]; becol[ni] = be[col]; wcol[ni] = lw[col];
        }
        #pragma unroll
        for (int mi = 0; mi < 2; ++mi)
            #pragma unroll
            for (int ni = 0; ni < 4; ++ni)
                #pragma unroll
                for (int r = 0; r < 4; ++r)
                    acc[mi][ni][r] = fmaxf(acc[mi][ni][r] + bcol[ni], 0.f);

        #pragma unroll
        for (int mi = 0; mi < 2; ++mi)
            #pragma unroll
            for (int r = 0; r < 4; ++r) {
                float s = acc[mi][0][r] + acc[mi][1][r] + acc[mi][2][r] + acc[mi][3][r];
                float q = acc[mi][0][r] * acc[mi][0][r] + acc[mi][1][r] * acc[mi][1][r]
                        + acc[mi][2][r] * acc[mi][2][r] + acc[mi][3][r] * acc[mi][3][r];
                #pragma unroll
                for (int off = 1; off < 16; off <<= 1) {
                    s += __shfl_xor(s, off);
                    q += __shfl_xor(q, off);
                }
                if (lr == 0) {
                    int R = wmi * 32 + mi * 16 + grp * 4 + r;
                    lnS[wni][R] = s; lnQ[wni][R] = q;
                }
            }
        __syncthreads();
        #pragma unroll
        for (int mi = 0; mi < 2; ++mi)
            #pragma unroll
            for (int r = 0; r < 4; ++r) {
                int R = wmi * 32 + mi * 16 + grp * 4 + r;
                float mu = (lnS[0][R] + lnS[1][R] + lnS[2][R] + lnS[3][R]) * (1.f / 256.f);
                float var = (lnQ[0][R] + lnQ[1][R] + lnQ[2][R] + lnQ[3][R]) * (1.f / 256.f) - mu * mu;
                float rs = rsqrtf(var + 1e-5f);
                float d = ((acc[mi][0][r] - mu) * rs * gcol[0] + becol[0]) * wcol[0]
                        + ((acc[mi][1][r] - mu) * rs * gcol[1] + becol[1]) * wcol[1]
                        + ((acc[mi][2][r] - mu) * rs * gcol[2] + becol[2]) * wcol[2]
                        + ((acc[mi][3][r] - mu) * rs * gcol[3] + becol[3]) * wcol[3];
                #pragma unroll
                for (int off = 1; off < 16; off <<= 1) d += __shfl_xor(d, off);
                if (lr == 0) lnD[wni][R] = d;
            }
        __syncthreads();
        if (tid < 64) {
            float dd = lnD[0][tid] + lnD[1][tid] + lnD[2][tid] + lnD[3][tid] + lb[0];
            dur[(size_t)b * 512 + t_base + tid] = fmaxf(dd, 0.f);
        }
        asm volatile("" ::: "memory");
    }
    #undef STAGE_B
}

extern "C" void kernel_launch(void* const* d_in, const int* in_sizes, int n_in,
                              void* d_out, int out_size, void* d_ws, size_t ws_size,
                              hipStream_t stream) {
    const float* x   = (const float*)d_in[0];
    const float* w1  = (const float*)d_in[1];
    const float* b1  = (const float*)d_in[2];
    const float* g1  = (const float*)d_in[3];
    const float* be1 = (const float*)d_in[4];
    const float* w2  = (const float*)d_in[5];
    const float* b2  = (const float*)d_in[6];
    const float* g2  = (const float*)d_in[7];
    const float* be2 = (const float*)d_in[8];
    const float* lw  = (const float*)d_in[9];
    const float* lb  = (const float*)d_in[10];
    const int* tgt   = (const int*)d_in[11];
    float* out = (float*)d_out;

    const int B = 32, T = 512, C = 256;
    const int rows = B * T;                       // 16384
    const int M = (out_size - rows) / (B * C);    // 3584

    char* ws = (char*)d_ws;
    unsigned short* w1p = (unsigned short*)(ws);              //   393,216 B
    unsigned short* w2p = (unsigned short*)(ws + 393216);     //   393,216 B
    unsigned short* h1b = (unsigned short*)(ws + 786432);     // 8,388,608 B
    int* cum            = (int*)(ws + 9175040);               //    65,536 B

    // ---- real pipeline (identical to round 4) ----
    prep<1><<<800, 512, 0, stream>>>(w1, w2, w1p, w2p, tgt, cum);
    conv1_hetero<1><<<2048, 512, 0, stream>>>(x, w1p, b1, g1, be1, h1b, cum, out, M);
    conv2_hetero<1><<<2048, 512, 0, stream>>>(h1b, w2p, b2, g2, be2, lw, lb,
                                              out + (size_t)B * M * C, cum, x, out, M);

    // ---- idempotent amplified probes (measurement only; rewrite same values) ----
    prep<16><<<800, 512, 0, stream>>>(w1, w2, w1p, w2p, tgt, cum);
    conv1_hetero<8><<<2048, 512, 0, stream>>>(x, w1p, b1, g1, be1, h1b, cum, out, M);
    conv2_hetero<8><<<2048, 512, 0, stream>>>(h1b, w2p, b2, g2, be2, lw, lb,
                                              out + (size_t)B * M * C, cum, x, out, M);
}

// Round 6
// 58.494 us; speedup vs baseline: 12.0085x; 12.0085x over previous
//
#include <hip/hip_runtime.h>
#include <hip/hip_bf16.h>

typedef float f32x4 __attribute__((ext_vector_type(4)));
typedef __bf16 bf16x8 __attribute__((ext_vector_type(8)));

static __device__ __forceinline__ unsigned short f2bf(float f) {
    unsigned int u = __float_as_uint(f);
    unsigned int r = (u + 0x7fffu + ((u >> 16) & 1u)) >> 16;   // RNE
    return (unsigned short)r;
}

// async global->LDS, 16B per lane; LDS dest = wave-uniform base + lane*16
static __device__ __forceinline__ void gll16(const void* g, void* l) {
    __builtin_amdgcn_global_load_lds(
        (const __attribute__((address_space(1))) unsigned int*)g,
        (__attribute__((address_space(3))) unsigned int*)l, 16, 0, 0);
}

// ---------------------------------------------------------------------------
// prep: pack both conv weights (tile-major MFMA-ready) + cumsum + idx-expand.
// idx[b][m] = token index whose frame range contains m, or -1 past total.
// ---------------------------------------------------------------------------
__global__ __launch_bounds__(512) void prep(
    const float* __restrict__ w1, const float* __restrict__ w2,
    unsigned short* __restrict__ w1p, unsigned short* __restrict__ w2p,
    const int* __restrict__ tgt, short* __restrict__ idxT, int M)
{
    int blk = blockIdx.x;
    if (blk < 768) {
        int gi = blk * 512 + threadIdx.x;            // 0..393215
        const float* w = (gi < 196608) ? w1 : w2;
        unsigned short* wp = (gi < 196608) ? w1p : w2p;
        int j = (gi < 196608) ? gi : gi - 196608;    // 0..196607
        int e = j & 7;
        int ch = j >> 3;                             // 0..24575
        int kt = ch >> 10;                           // 0..23
        int rem = ch & 1023;
        int nb = rem >> 6, l = rem & 63;
        int n = nb * 16 + (l & 15);
        int cin = (kt & 7) * 32 + (l >> 4) * 8 + e;
        int kk = kt >> 3;
        wp[j] = f2bf(w[n * 768 + cin * 3 + kk]);
    } else {
        __shared__ int s[512];
        int b = blk - 768, tid = threadIdx.x;
        int d = tgt[b * 512 + tid];
        s[tid] = d;
        __syncthreads();
        for (int off = 1; off < 512; off <<= 1) {
            int v = (tid >= off) ? s[tid - off] : 0;
            __syncthreads();
            s[tid] += v;
            __syncthreads();
        }
        int myend = s[tid];          // inclusive cumsum
        int mystart = myend - d;
        short* row = idxT + (size_t)b * M;
        for (int p = mystart; p < myend; ++p) row[p] = (short)tid;
        __syncthreads();
        int total = s[511];
        for (int p = total + tid; p < M; p += 512) row[p] = (short)-1;
    }
}

// ---------------------------------------------------------------------------
// gather part: 32 mel rows / block, 8 waves; direct idx lookup (no search)
// ---------------------------------------------------------------------------
static __device__ __forceinline__ void gather_part(
    int gblk, int phase, const float* __restrict__ x, const short* __restrict__ idxT,
    float* __restrict__ out, int M, int wv, int lane)
{
    int b = gblk / 56;
    int r0 = (gblk % 56) * 32 + phase;
    const short* row = idxT + (size_t)b * M;
    int id[4];
    #pragma unroll
    for (int i = 0; i < 4; ++i) id[i] = row[r0 + i * 8 + wv];
    #pragma unroll
    for (int i = 0; i < 4; ++i) {
        int m = r0 + i * 8 + wv;
        float4 v = make_float4(0.f, 0.f, 0.f, 0.f);
        if (id[i] >= 0)
            v = *reinterpret_cast<const float4*>(x + ((size_t)(b * 512 + id[i])) * 256 + lane * 4);
        *reinterpret_cast<float4*>(out + ((size_t)b * M + m) * 256 + lane * 4) = v;
    }
}

// ---------------------------------------------------------------------------
// conv1 + gather(first half). BM=64, BN=256, BK=32 (24 tiles), 8 waves 2Mx4N.
// ---------------------------------------------------------------------------
__global__ __launch_bounds__(512, 4) void conv1_hetero(
    const float* __restrict__ x, const unsigned short* __restrict__ Wp,
    const float* __restrict__ bias, const float* __restrict__ g,
    const float* __restrict__ be, unsigned short* __restrict__ h1b,
    const short* __restrict__ idxT, float* __restrict__ out, int M)
{
    __shared__ __align__(16) unsigned short As[66 * 256];
    __shared__ __align__(16) unsigned short Bsm[2][8192];
    __shared__ float lnS[4][64], lnQ[4][64];

    const int tid = threadIdx.x;
    const int lane = tid & 63;
    const int wv = tid >> 6;

    if (blockIdx.x >= 256) {
        gather_part(blockIdx.x - 256, 0, x, idxT, out, M, wv, lane);
        return;
    }

    const int wmi = wv >> 2, wni = wv & 3;
    const int grp = lane >> 4, lr = lane & 15;
    const int b = blockIdx.x >> 3;
    const int t_base = (blockIdx.x & 7) * 64;

    // ---- A stage: x rows t_base-1 .. t_base+64 -> bf16, XOR-swizzled (row&7)<<3
    #pragma unroll
    for (int i = 0; i < 9; ++i) {
        int cc = i * 512 + tid;
        if (cc < 66 * 64) {
            int row = cc >> 6, q = cc & 63;
            int tt = t_base - 1 + row;
            ushort4 o = make_ushort4(0, 0, 0, 0);
            if ((unsigned)tt < 512u) {
                float4 v = *reinterpret_cast<const float4*>(x + ((size_t)(b * 512 + tt)) * 256 + q * 4);
                o.x = f2bf(v.x); o.y = f2bf(v.y); o.z = f2bf(v.z); o.w = f2bf(v.w);
            }
            *reinterpret_cast<ushort4*>(&As[row * 256 + ((q * 4) ^ ((row & 7) << 3))]) = o;
        }
    }

    // ---- B double-buffered pipeline via global_load_lds
    const char* wpB = (const char*)Wp;
    char* bs0 = (char*)&Bsm[0][0];
    #define STAGE_B(kt, buf) do {                                              \
        const char* _s = wpB + (kt) * 16384 + wv * 2048 + lane * 16;           \
        char* _d = bs0 + (buf) * 16384 + wv * 2048;                            \
        gll16(_s, _d); gll16(_s + 1024, _d + 1024);                            \
    } while (0)

    STAGE_B(0, 0);
    __syncthreads();

    f32x4 acc[2][4] = {};
    int cur = 0;
    for (int kt = 0; kt < 24; ++kt) {
        if (kt < 23) STAGE_B(kt + 1, cur ^ 1);
        const int kk = kt >> 3, cin0 = (kt & 7) * 32;
        bf16x8 af[2], bfr[4];
        #pragma unroll
        for (int mi = 0; mi < 2; ++mi) {
            int tr = wmi * 32 + mi * 16 + lr + kk;
            af[mi] = *reinterpret_cast<const bf16x8*>(&As[tr * 256 + ((cin0 + grp * 8) ^ ((tr & 7) << 3))]);
        }
        #pragma unroll
        for (int ni = 0; ni < 4; ++ni)
            bfr[ni] = *reinterpret_cast<const bf16x8*>(&Bsm[cur][(wni * 4 + ni) * 512 + lane * 8]);
        __builtin_amdgcn_s_setprio(1);
        #pragma unroll
        for (int mi = 0; mi < 2; ++mi)
            #pragma unroll
            for (int ni = 0; ni < 4; ++ni)
                acc[mi][ni] = __builtin_amdgcn_mfma_f32_16x16x32_bf16(af[mi], bfr[ni], acc[mi][ni], 0, 0, 0);
        __builtin_amdgcn_s_setprio(0);
        __syncthreads();
        cur ^= 1;
    }

    // ---- epilogue: bias+relu, LN, LDS-staged vectorized bf16 store
    float bcol[4], gcol[4], becol[4];
    #pragma unroll
    for (int ni = 0; ni < 4; ++ni) {
        int col = wni * 64 + ni * 16 + lr;
        bcol[ni] = bias[col]; gcol[ni] = g[col]; becol[ni] = be[col];
    }
    #pragma unroll
    for (int mi = 0; mi < 2; ++mi)
        #pragma unroll
        for (int ni = 0; ni < 4; ++ni)
            #pragma unroll
            for (int r = 0; r < 4; ++r)
                acc[mi][ni][r] = fmaxf(acc[mi][ni][r] + bcol[ni], 0.f);

    #pragma unroll
    for (int mi = 0; mi < 2; ++mi)
        #pragma unroll
        for (int r = 0; r < 4; ++r) {
            float s = acc[mi][0][r] + acc[mi][1][r] + acc[mi][2][r] + acc[mi][3][r];
            float q = acc[mi][0][r] * acc[mi][0][r] + acc[mi][1][r] * acc[mi][1][r]
                    + acc[mi][2][r] * acc[mi][2][r] + acc[mi][3][r] * acc[mi][3][r];
            #pragma unroll
            for (int off = 1; off < 16; off <<= 1) {
                s += __shfl_xor(s, off);
                q += __shfl_xor(q, off);
            }
            if (lr == 0) {
                int R = wmi * 32 + mi * 16 + grp * 4 + r;
                lnS[wni][R] = s; lnQ[wni][R] = q;
            }
        }
    __syncthreads();

    unsigned short* Hs = &Bsm[0][0];   // 32 KB, dead after K-loop
    #pragma unroll
    for (int mi = 0; mi < 2; ++mi)
        #pragma unroll
        for (int r = 0; r < 4; ++r) {
            int R = wmi * 32 + mi * 16 + grp * 4 + r;
            float mu = (lnS[0][R] + lnS[1][R] + lnS[2][R] + lnS[3][R]) * (1.f / 256.f);
            float var = (lnQ[0][R] + lnQ[1][R] + lnQ[2][R] + lnQ[3][R]) * (1.f / 256.f) - mu * mu;
            float rs = rsqrtf(var + 1e-5f);
            #pragma unroll
            for (int ni = 0; ni < 4; ++ni) {
                int col = wni * 64 + ni * 16 + lr;
                float h = (acc[mi][ni][r] - mu) * rs * gcol[ni] + becol[ni];
                Hs[R * 256 + (col ^ ((R & 7) << 3))] = f2bf(h);   // keep conv2's swizzle
            }
        }
    __syncthreads();
    // linear copy preserves the baked-in swizzle; fully coalesced 16B stores
    #pragma unroll
    for (int i = 0; i < 4; ++i) {
        int c = i * 512 + tid;          // 2048 chunks of 16B
        int row = c >> 5, seg = c & 31;
        uint4 v = *reinterpret_cast<const uint4*>(&Hs[row * 256 + seg * 8]);
        *reinterpret_cast<uint4*>(h1b + ((size_t)(b * 512 + t_base + row)) * 256 + seg * 8) = v;
    }
    #undef STAGE_B
}

// ---------------------------------------------------------------------------
// conv2 + LN + linear + relu -> dur, + gather(second half)
// ---------------------------------------------------------------------------
__global__ __launch_bounds__(512, 4) void conv2_hetero(
    const unsigned short* __restrict__ h1b, const unsigned short* __restrict__ Wp,
    const float* __restrict__ bias, const float* __restrict__ g,
    const float* __restrict__ be, const float* __restrict__ lw,
    const float* __restrict__ lb, float* __restrict__ dur,
    const short* __restrict__ idxT, const float* __restrict__ x,
    float* __restrict__ out, int M)
{
    __shared__ __align__(16) unsigned short As[66 * 256];
    __shared__ __align__(16) unsigned short Bsm[2][8192];
    __shared__ float lnS[4][64], lnQ[4][64], lnD[4][64];

    const int tid = threadIdx.x;
    const int lane = tid & 63;
    const int wv = tid >> 6;

    if (blockIdx.x >= 256) {
        gather_part(blockIdx.x - 256, 1792, x, idxT, out, M, wv, lane);
        return;
    }

    const int wmi = wv >> 2, wni = wv & 3;
    const int grp = lane >> 4, lr = lane & 15;
    const int b = blockIdx.x >> 3;
    const int t_base = (blockIdx.x & 7) * 64;

    // ---- A stage: interior rows 1..64 via global_load_lds (h1b is pre-swizzled)
    {
        const char* src = (const char*)h1b + ((size_t)(b * 512 + t_base)) * 512 + wv * 4096 + lane * 16;
        char* dst = (char*)&As[256] + wv * 4096;
        #pragma unroll
        for (int i = 0; i < 4; ++i) gll16(src + i * 1024, dst + i * 1024);
    }
    // halo rows 0 (t_base-1) and 65 (t_base+64), zero-padded
    if (tid < 32) {
        int tt = t_base - 1;
        uint4 v = make_uint4(0u, 0u, 0u, 0u);
        if (tt >= 0)
            v = *reinterpret_cast<const uint4*>((const char*)h1b + ((size_t)(b * 512 + tt)) * 512 + tid * 16);
        *reinterpret_cast<uint4*>((char*)As + tid * 16) = v;
    } else if (tid < 64) {
        int t2 = tid - 32, tt = t_base + 64;
        uint4 v = make_uint4(0u, 0u, 0u, 0u);
        if (tt < 512)
            v = *reinterpret_cast<const uint4*>((const char*)h1b + ((size_t)(b * 512 + tt)) * 512 + t2 * 16);
        *reinterpret_cast<uint4*>((char*)&As[65 * 256] + t2 * 16) = v;
    }

    const char* wpB = (const char*)Wp;
    char* bs0 = (char*)&Bsm[0][0];
    #define STAGE_B(kt, buf) do {                                              \
        const char* _s = wpB + (kt) * 16384 + wv * 2048 + lane * 16;           \
        char* _d = bs0 + (buf) * 16384 + wv * 2048;                            \
        gll16(_s, _d); gll16(_s + 1024, _d + 1024);                            \
    } while (0)

    STAGE_B(0, 0);
    __syncthreads();

    f32x4 acc[2][4] = {};
    int cur = 0;
    for (int kt = 0; kt < 24; ++kt) {
        if (kt < 23) STAGE_B(kt + 1, cur ^ 1);
        const int kk = kt >> 3, cin0 = (kt & 7) * 32;
        bf16x8 af[2], bfr[4];
        #pragma unroll
        for (int mi = 0; mi < 2; ++mi) {
            int tr = wmi * 32 + mi * 16 + lr + kk;
            // h1b swizzle follows absolute t = t_base + tr - 1 -> bits (tr+7)&7
            af[mi] = *reinterpret_cast<const bf16x8*>(&As[tr * 256 + ((cin0 + grp * 8) ^ (((tr + 7) & 7) << 3))]);
        }
        #pragma unroll
        for (int ni = 0; ni < 4; ++ni)
            bfr[ni] = *reinterpret_cast<const bf16x8*>(&Bsm[cur][(wni * 4 + ni) * 512 + lane * 8]);
        __builtin_amdgcn_s_setprio(1);
        #pragma unroll
        for (int mi = 0; mi < 2; ++mi)
            #pragma unroll
            for (int ni = 0; ni < 4; ++ni)
                acc[mi][ni] = __builtin_amdgcn_mfma_f32_16x16x32_bf16(af[mi], bfr[ni], acc[mi][ni], 0, 0, 0);
        __builtin_amdgcn_s_setprio(0);
        __syncthreads();
        cur ^= 1;
    }

    // ---- epilogue: bias+relu, LN, dot lin_w, relu -> dur[64]
    float bcol[4], gcol[4], becol[4], wcol[4];
    #pragma unroll
    for (int ni = 0; ni < 4; ++ni) {
        int col = wni * 64 + ni * 16 + lr;
        bcol[ni] = bias[col]; gcol[ni] = g[col]; becol[ni] = be[col]; wcol[ni] = lw[col];
    }
    #pragma unroll
    for (int mi = 0; mi < 2; ++mi)
        #pragma unroll
        for (int ni = 0; ni < 4; ++ni)
            #pragma unroll
            for (int r = 0; r < 4; ++r)
                acc[mi][ni][r] = fmaxf(acc[mi][ni][r] + bcol[ni], 0.f);

    #pragma unroll
    for (int mi = 0; mi < 2; ++mi)
        #pragma unroll
        for (int r = 0; r < 4; ++r) {
            float s = acc[mi][0][r] + acc[mi][1][r] + acc[mi][2][r] + acc[mi][3][r];
            float q = acc[mi][0][r] * acc[mi][0][r] + acc[mi][1][r] * acc[mi][1][r]
                    + acc[mi][2][r] * acc[mi][2][r] + acc[mi][3][r] * acc[mi][3][r];
            #pragma unroll
            for (int off = 1; off < 16; off <<= 1) {
                s += __shfl_xor(s, off);
                q += __shfl_xor(q, off);
            }
            if (lr == 0) {
                int R = wmi * 32 + mi * 16 + grp * 4 + r;
                lnS[wni][R] = s; lnQ[wni][R] = q;
            }
        }
    __syncthreads();
    #pragma unroll
    for (int mi = 0; mi < 2; ++mi)
        #pragma unroll
        for (int r = 0; r < 4; ++r) {
            int R = wmi * 32 + mi * 16 + grp * 4 + r;
            float mu = (lnS[0][R] + lnS[1][R] + lnS[2][R] + lnS[3][R]) * (1.f / 256.f);
            float var = (lnQ[0][R] + lnQ[1][R] + lnQ[2][R] + lnQ[3][R]) * (1.f / 256.f) - mu * mu;
            float rs = rsqrtf(var + 1e-5f);
            float d = ((acc[mi][0][r] - mu) * rs * gcol[0] + becol[0]) * wcol[0]
                    + ((acc[mi][1][r] - mu) * rs * gcol[1] + becol[1]) * wcol[1]
                    + ((acc[mi][2][r] - mu) * rs * gcol[2] + becol[2]) * wcol[2]
                    + ((acc[mi][3][r] - mu) * rs * gcol[3] + becol[3]) * wcol[3];
            #pragma unroll
            for (int off = 1; off < 16; off <<= 1) d += __shfl_xor(d, off);
            if (lr == 0) lnD[wni][R] = d;
        }
    __syncthreads();
    if (tid < 64) {
        float dd = lnD[0][tid] + lnD[1][tid] + lnD[2][tid] + lnD[3][tid] + lb[0];
        dur[(size_t)b * 512 + t_base + tid] = fmaxf(dd, 0.f);
    }
    #undef STAGE_B
}

extern "C" void kernel_launch(void* const* d_in, const int* in_sizes, int n_in,
                              void* d_out, int out_size, void* d_ws, size_t ws_size,
                              hipStream_t stream) {
    const float* x   = (const float*)d_in[0];
    const float* w1  = (const float*)d_in[1];
    const float* b1  = (const float*)d_in[2];
    const float* g1  = (const float*)d_in[3];
    const float* be1 = (const float*)d_in[4];
    const float* w2  = (const float*)d_in[5];
    const float* b2  = (const float*)d_in[6];
    const float* g2  = (const float*)d_in[7];
    const float* be2 = (const float*)d_in[8];
    const float* lw  = (const float*)d_in[9];
    const float* lb  = (const float*)d_in[10];
    const int* tgt   = (const int*)d_in[11];
    float* out = (float*)d_out;

    const int B = 32, T = 512, C = 256;
    const int rows = B * T;                       // 16384
    const int M = (out_size - rows) / (B * C);    // 3584

    char* ws = (char*)d_ws;
    unsigned short* w1p = (unsigned short*)(ws);              //   393,216 B
    unsigned short* w2p = (unsigned short*)(ws + 393216);     //   393,216 B
    unsigned short* h1b = (unsigned short*)(ws + 786432);     // 8,388,608 B
    short* idxT         = (short*)(ws + 9175040);             //   229,376 B

    prep<<<800, 512, 0, stream>>>(w1, w2, w1p, w2p, tgt, idxT, M);
    // grid = 256 conv blocks + 32 batches * 56 gather blocks = 2048
    conv1_hetero<<<2048, 512, 0, stream>>>(x, w1p, b1, g1, be1, h1b, idxT, out, M);
    conv2_hetero<<<2048, 512, 0, stream>>>(h1b, w2p, b2, g2, be2, lw, lb,
                                           out + (size_t)B * M * C, idxT, x, out, M);
}